// Round 1
// baseline (435.951 us; speedup 1.0000x reference)
//
#include <hip/hip_runtime.h>
#include <cstdint>
#include <cstddef>

// MHA: out = softmax_causal((XqWq^T+bq)(XkWk^T+bk)^T / 8) (XvWv^T+bv) Wo^T + bo
// B=4 S=2048 D=1024 H=16 dk=64. All compute in bf16 MFMA, fp32 accum.
// ws layout (bytes): [0,16M) Xq_bf16 -> later Vp ; [16M,32M) Xk_bf16 -> later Xattn ;
// [32M,48M) Xv_bf16 -> later Vt ; [48M,56M) 4x weights bf16 ; [56M,72M) Qp ; [72M,88M) Kp.
// Requires ws_size >= 88 MiB.

typedef __attribute__((ext_vector_type(8))) short bf16x8;
typedef __attribute__((ext_vector_type(4))) float f32x4;

__device__ __forceinline__ unsigned short f2bf(float f) {
  union { float f; unsigned u; } x; x.f = f;
  unsigned r = x.u + 0x7FFFu + ((x.u >> 16) & 1u);   // RNE
  return (unsigned short)(r >> 16);
}

__device__ __forceinline__ void gld16(unsigned short* lds, const unsigned short* g) {
  __builtin_amdgcn_global_load_lds(
      (const __attribute__((address_space(1))) unsigned int*)g,
      (__attribute__((address_space(3))) unsigned int*)lds, 16, 0, 0);
}

// ---------------- fp32 -> bf16 cast (vectorized) ----------------
__global__ __launch_bounds__(256) void cast_bf16(const float* __restrict__ src,
                                                 unsigned short* __restrict__ dst, int n4) {
  const int i = blockIdx.x * 256 + threadIdx.x;
  if (i >= n4) return;
  const float4 f = ((const float4*)src)[i];
  ushort4 o;
  o.x = f2bf(f.x); o.y = f2bf(f.y); o.z = f2bf(f.z); o.w = f2bf(f.w);
  ((ushort4*)dst)[i] = o;
}

// ---------------- GEMM: C[m,n] = sum_k A[m,k]*W[n,k] + bias[n] ----------------
// m97 structure: 128x128 tile, BK=32, 4 waves (each 64x64), global_load_lds w=16.
template <bool F32OUT>
__global__ __launch_bounds__(256)
void gemm_bt(const unsigned short* __restrict__ A,   // [M,K] bf16
             const unsigned short* __restrict__ Bw,  // [N,K] bf16
             const float* __restrict__ bias,         // [N]
             unsigned short* __restrict__ Cb,        // [M,N] bf16 (if !F32OUT)
             float* __restrict__ Cf,                 // [M,N] f32  (if F32OUT)
             int M, int N, int K) {
  __shared__ unsigned short As[128 * 32];
  __shared__ unsigned short Bs[128 * 32];
  const int tid = threadIdx.x;
  const int lane = tid & 63;
  const int w = tid >> 6;
  const int wm = (w >> 1) * 64;
  const int wn = (w & 1) * 64;
  const int m0 = blockIdx.y * 128;
  const int n0 = blockIdx.x * 128;
  const int l15 = lane & 15, l4 = lane >> 4;

  f32x4 acc[4][4] = {};

  // staging chunks: chunk c in [0,512) covers 16B; row=c>>2, k-chunk=(c&3)*8
  const int c0 = tid, c1 = 256 + tid;
  const int r0 = c0 >> 2, kc0 = (c0 & 3) * 8;
  const int r1 = c1 >> 2, kc1 = (c1 & 3) * 8;

  for (int k0 = 0; k0 < K; k0 += 32) {
    __syncthreads();  // previous tile's reads done
    gld16(&As[c0 * 8], &A[(size_t)(m0 + r0) * K + k0 + kc0]);
    gld16(&As[c1 * 8], &A[(size_t)(m0 + r1) * K + k0 + kc1]);
    gld16(&Bs[c0 * 8], &Bw[(size_t)(n0 + r0) * K + k0 + kc0]);
    gld16(&Bs[c1 * 8], &Bw[(size_t)(n0 + r1) * K + k0 + kc1]);
    __syncthreads();  // drains vmcnt (compiler emits vmcnt(0) before s_barrier)

    bf16x8 af[4], bfr[4];
#pragma unroll
    for (int m = 0; m < 4; ++m)
      af[m] = *(const bf16x8*)&As[(wm + m * 16 + l15) * 32 + l4 * 8];
#pragma unroll
    for (int n = 0; n < 4; ++n)
      bfr[n] = *(const bf16x8*)&Bs[(wn + n * 16 + l15) * 32 + l4 * 8];
#pragma unroll
    for (int m = 0; m < 4; ++m)
#pragma unroll
      for (int n = 0; n < 4; ++n)
        acc[m][n] = __builtin_amdgcn_mfma_f32_16x16x32_bf16(af[m], bfr[n], acc[m][n], 0, 0, 0);
  }

  // epilogue: D row=(lane>>4)*4+j, col=lane&15  [m89 verified mapping]
  const int crow = l4 * 4;
#pragma unroll
  for (int m = 0; m < 4; ++m) {
#pragma unroll
    for (int n = 0; n < 4; ++n) {
      const int col = n0 + wn + n * 16 + l15;
      const float bv_ = bias[col];
#pragma unroll
      for (int j = 0; j < 4; ++j) {
        const int row = m0 + wm + m * 16 + crow + j;
        const float v = acc[m][n][j] + bv_;
        if constexpr (F32OUT) Cf[(size_t)row * N + col] = v;
        else                  Cb[(size_t)row * N + col] = f2bf(v);
      }
    }
  }
}

// ---------------- V transpose: [b,s,h*64+d] -> [(b*16+h)*64+d, s] ----------------
__global__ __launch_bounds__(256)
void transpose_v(const unsigned short* __restrict__ Vp, unsigned short* __restrict__ Vt) {
  constexpr int S = 2048, Dm = 1024;
  __shared__ __align__(16) unsigned short t[64][72];  // pad to keep 16B align + spread banks
  const int bh = blockIdx.x, b = bh >> 4, h = bh & 15;
  const int s0 = blockIdx.y * 64;
  const int tid = threadIdx.x;
#pragma unroll
  for (int r = 0; r < 2; ++r) {
    const int c = r * 256 + tid;
    const int sl = c >> 3, d8 = (c & 7) * 8;
    *(bf16x8*)&t[sl][d8] =
        *(const bf16x8*)&Vp[(size_t)(b * S + s0 + sl) * Dm + h * 64 + d8];
  }
  __syncthreads();
#pragma unroll
  for (int r = 0; r < 2; ++r) {
    const int c = r * 256 + tid;
    const int dl = c >> 3, s8 = (c & 7) * 8;
    bf16x8 ov;
#pragma unroll
    for (int jj = 0; jj < 8; ++jj) ov[jj] = t[s8 + jj][dl];
    *(bf16x8*)&Vt[(size_t)(bh * 64 + dl) * S + s0 + s8] = ov;
  }
}

// ---------------- flash attention, causal ----------------
// 4 independent waves/block, 16 q-rows per wave, KVBLK=32, online softmax.
__global__ __launch_bounds__(256)
void attn_fwd(const unsigned short* __restrict__ Qp,  // [B*S, 1024] bf16
              const unsigned short* __restrict__ Kp,  // [B*S, 1024] bf16
              const unsigned short* __restrict__ Vt,  // [(b*16+h)*64+d, S] bf16
              unsigned short* __restrict__ Xo) {      // [B*S, 1024] bf16
  constexpr int S = 2048, Dm = 1024;
  const int bh = blockIdx.x;
  const int b = bh >> 4, h = bh & 15;
  const int w = threadIdx.x >> 6;
  const int lane = threadIdx.x & 63;
  const int l15 = lane & 15, l4 = lane >> 4;
  const int q0 = blockIdx.y * 64 + w * 16;

  __shared__ __align__(16) unsigned short pbuf[4][16][48];  // per-wave P bounce, padded

  // Q A-operand frags: lane row=l15, k-chunk=l4*8 (two 32-wide d chunks)
  const unsigned short* qb = Qp + (size_t)(b * S + q0 + l15) * Dm + h * 64 + l4 * 8;
  const bf16x8 qf0 = *(const bf16x8*)qb;
  const bf16x8 qf1 = *(const bf16x8*)(qb + 32);

  f32x4 o[4] = {};
  float mrow[4] = {-1e30f, -1e30f, -1e30f, -1e30f};
  float lsum[4] = {0.f, 0.f, 0.f, 0.f};

  const unsigned short* kb0 = Kp + (size_t)(b * S) * Dm + h * 64 + l4 * 8;
  const unsigned short* vb0 = Vt + (size_t)(bh * 64 + l15) * S + l4 * 8;

  const int kv_end = q0 + 16;  // causal: keys < q0+16 for this wave's rows
  for (int kv0 = 0; kv0 < kv_end; kv0 += 32) {
    f32x4 s[2];
#pragma unroll
    for (int c = 0; c < 2; ++c) {
      const unsigned short* kb = kb0 + (size_t)(kv0 + c * 16 + l15) * Dm;
      const bf16x8 kf0 = *(const bf16x8*)kb;
      const bf16x8 kf1 = *(const bf16x8*)(kb + 32);
      f32x4 z = {};
      z = __builtin_amdgcn_mfma_f32_16x16x32_bf16(qf0, kf0, z, 0, 0, 0);
      z = __builtin_amdgcn_mfma_f32_16x16x32_bf16(qf1, kf1, z, 0, 0, 0);
      s[c] = z;
    }
    // online softmax; D frag: row q = q0 + l4*4 + j, col key = kv0 + c*16 + l15
#pragma unroll
    for (int j = 0; j < 4; ++j) {
      const int qrow = q0 + l4 * 4 + j;
      float s0 = s[0][j] * 0.125f;
      float s1 = s[1][j] * 0.125f;
      if (kv0 + l15 > qrow) s0 = -1e9f;
      if (kv0 + 16 + l15 > qrow) s1 = -1e9f;
      float mx = fmaxf(s0, s1);
#pragma unroll
      for (int off = 1; off < 16; off <<= 1) mx = fmaxf(mx, __shfl_xor(mx, off));
      const float mnew = fmaxf(mrow[j], mx);
      const float fct = __expf(mrow[j] - mnew);
      mrow[j] = mnew;
      const float p0 = __expf(s0 - mnew);
      const float p1 = __expf(s1 - mnew);
      float ps = p0 + p1;
#pragma unroll
      for (int off = 1; off < 16; off <<= 1) ps += __shfl_xor(ps, off);
      lsum[j] = lsum[j] * fct + ps;
#pragma unroll
      for (int d = 0; d < 4; ++d) o[d][j] *= fct;
      const int prow = l4 * 4 + j;
      pbuf[w][prow][l15] = f2bf(p0);
      pbuf[w][prow][16 + l15] = f2bf(p1);
    }
    asm volatile("s_waitcnt lgkmcnt(0)" ::: "memory");  // cross-lane P visible (per-wave buf)
    const bf16x8 pa = *(const bf16x8*)&pbuf[w][l15][l4 * 8];  // A-op: row=l15, k=l4*8
#pragma unroll
    for (int d = 0; d < 4; ++d) {
      const bf16x8 vf = *(const bf16x8*)(vb0 + (size_t)(d * 16) * S + kv0);  // B-op from Vt
      o[d] = __builtin_amdgcn_mfma_f32_16x16x32_bf16(pa, vf, o[d], 0, 0, 0);
    }
  }
  // normalize + store
#pragma unroll
  for (int d = 0; d < 4; ++d) {
#pragma unroll
    for (int j = 0; j < 4; ++j) {
      const int row = q0 + l4 * 4 + j;
      const float v = o[d][j] / lsum[j];
      Xo[(size_t)(b * S + row) * Dm + h * 64 + d * 16 + l15] = f2bf(v);
    }
  }
}

// ---------------- launch ----------------
extern "C" void kernel_launch(void* const* d_in, const int* in_sizes, int n_in,
                              void* d_out, int out_size, void* d_ws, size_t ws_size,
                              hipStream_t stream) {
  const float* query = (const float*)d_in[0];
  const float* key   = (const float*)d_in[1];
  const float* value = (const float*)d_in[2];
  // d_in[3] = mask: guaranteed causal tril by setup; handled analytically.
  const float* Wq = (const float*)d_in[4];
  const float* bq = (const float*)d_in[5];
  const float* Wk = (const float*)d_in[6];
  const float* bk = (const float*)d_in[7];
  const float* Wv = (const float*)d_in[8];
  const float* bv = (const float*)d_in[9];
  const float* Wo = (const float*)d_in[10];
  const float* bo = (const float*)d_in[11];

  constexpr int B = 4, S = 2048, D = 1024;
  constexpr int M = B * S;  // 8192
  const size_t MB = 1024u * 1024u;
  uint8_t* ws = (uint8_t*)d_ws;

  unsigned short* Xq  = (unsigned short*)(ws + 0);        // 16M
  unsigned short* Xk  = (unsigned short*)(ws + 16 * MB);  // 16M
  unsigned short* Xv  = (unsigned short*)(ws + 32 * MB);  // 16M
  unsigned short* Wqb = (unsigned short*)(ws + 48 * MB);  // 2M
  unsigned short* Wkb = (unsigned short*)(ws + 50 * MB);
  unsigned short* Wvb = (unsigned short*)(ws + 52 * MB);
  unsigned short* Wob = (unsigned short*)(ws + 54 * MB);
  unsigned short* Qp  = (unsigned short*)(ws + 56 * MB);  // 16M
  unsigned short* Kp  = (unsigned short*)(ws + 72 * MB);  // 16M
  unsigned short* Vp  = (unsigned short*)(ws + 0);        // reuse Xq (after Q gemm)
  unsigned short* Vt  = (unsigned short*)(ws + 32 * MB);  // reuse Xv (after V gemm)
  unsigned short* Xat = (unsigned short*)(ws + 16 * MB);  // reuse Xk (after K gemm)

  // casts
  const int nAct4 = M * D / 4, nW4 = D * D / 4;
  cast_bf16<<<(nAct4 + 255) / 256, 256, 0, stream>>>(query, Xq, nAct4);
  cast_bf16<<<(nAct4 + 255) / 256, 256, 0, stream>>>(key,   Xk, nAct4);
  cast_bf16<<<(nAct4 + 255) / 256, 256, 0, stream>>>(value, Xv, nAct4);
  cast_bf16<<<(nW4 + 255) / 256, 256, 0, stream>>>(Wq, Wqb, nW4);
  cast_bf16<<<(nW4 + 255) / 256, 256, 0, stream>>>(Wk, Wkb, nW4);
  cast_bf16<<<(nW4 + 255) / 256, 256, 0, stream>>>(Wv, Wvb, nW4);
  cast_bf16<<<(nW4 + 255) / 256, 256, 0, stream>>>(Wo, Wob, nW4);

  // projections
  dim3 gg(D / 128, M / 128);  // (8, 64)
  gemm_bt<false><<<gg, 256, 0, stream>>>(Xq, Wqb, bq, Qp, nullptr, M, D, D);
  gemm_bt<false><<<gg, 256, 0, stream>>>(Xk, Wkb, bk, Kp, nullptr, M, D, D);
  gemm_bt<false><<<gg, 256, 0, stream>>>(Xv, Wvb, bv, Vp, nullptr, M, D, D);

  // V transpose for contiguous PV B-operand reads
  transpose_v<<<dim3(64, S / 64), 256, 0, stream>>>(Vp, Vt);

  // flash attention
  attn_fwd<<<dim3(64, S / 64), 256, 0, stream>>>(Qp, Kp, Vt, Xat);

  // output projection (fp32 out)
  gemm_bt<true><<<gg, 256, 0, stream>>>(Xat, Wob, bo, nullptr, (float*)d_out, M, D, D);
}

// Round 2
// 320.980 us; speedup vs baseline: 1.3582x; 1.3582x over previous
//
#include <hip/hip_runtime.h>
#include <cstdint>
#include <cstddef>

// MHA: out = softmax_causal((XqWq^T+bq)(XkWk^T+bk)^T / 8) (XvWv^T+bv) Wo^T + bo
// B=4 S=2048 D=1024 H=16 dk=64. bf16 MFMA, fp32 accum.
// ws: [0,16M) Xq->Vp ; [16M,32M) Xk->Xattn ; [32M,48M) Xv->Vt ;
// [48M,56M) weights bf16 ; [56M,72M) Qp (pre-scaled by 1/8) ; [72M,88M) Kp.

typedef __attribute__((ext_vector_type(8))) short bf16x8;
typedef __attribute__((ext_vector_type(4))) float f32x4;
typedef __attribute__((ext_vector_type(16))) float f32x16;

__device__ __forceinline__ unsigned short f2bf(float f) {
  union { float f; unsigned u; } x; x.f = f;
  unsigned r = x.u + 0x7FFFu + ((x.u >> 16) & 1u);   // RNE
  return (unsigned short)(r >> 16);
}

__device__ __forceinline__ unsigned cvtpk_bf16(float lo, float hi) {
  unsigned r;
  asm("v_cvt_pk_bf16_f32 %0, %1, %2" : "=v"(r) : "v"(lo), "v"(hi));
  return r;
}

__device__ __forceinline__ f32x16 mfma32(bf16x8 a, bf16x8 b, f32x16 c) {
  return __builtin_amdgcn_mfma_f32_32x32x16_bf16(a, b, c, 0, 0, 0);
}

__device__ __forceinline__ void gld16(unsigned short* lds, const unsigned short* g) {
  __builtin_amdgcn_global_load_lds(
      (const __attribute__((address_space(1))) unsigned int*)g,
      (__attribute__((address_space(3))) unsigned int*)lds, 16, 0, 0);
}

// ---------------- fp32 -> bf16 cast ----------------
__global__ __launch_bounds__(256) void cast_bf16(const float* __restrict__ src,
                                                 unsigned short* __restrict__ dst, int n4) {
  const int i = blockIdx.x * 256 + threadIdx.x;
  if (i >= n4) return;
  const float4 f = ((const float4*)src)[i];
  ushort4 o;
  o.x = f2bf(f.x); o.y = f2bf(f.y); o.z = f2bf(f.z); o.w = f2bf(f.w);
  ((ushort4*)dst)[i] = o;
}

// ---------------- GEMM: C[m,n] = sum_k A[m,k]*W[n,k] + bias[n] ----------------
template <bool F32OUT, bool SCALEQ>
__global__ __launch_bounds__(256)
void gemm_bt(const unsigned short* __restrict__ A,
             const unsigned short* __restrict__ Bw,
             const float* __restrict__ bias,
             unsigned short* __restrict__ Cb,
             float* __restrict__ Cf,
             int M, int N, int K) {
  __shared__ unsigned short As[128 * 32];
  __shared__ unsigned short Bs[128 * 32];
  const int tid = threadIdx.x;
  const int lane = tid & 63;
  const int w = tid >> 6;
  const int wm = (w >> 1) * 64;
  const int wn = (w & 1) * 64;
  const int m0 = blockIdx.y * 128;
  const int n0 = blockIdx.x * 128;
  const int l15 = lane & 15, l4 = lane >> 4;

  f32x4 acc[4][4] = {};

  const int c0 = tid, c1 = 256 + tid;
  const int r0 = c0 >> 2, kc0 = (c0 & 3) * 8;
  const int r1 = c1 >> 2, kc1 = (c1 & 3) * 8;

  for (int k0 = 0; k0 < K; k0 += 32) {
    __syncthreads();
    gld16(&As[c0 * 8], &A[(size_t)(m0 + r0) * K + k0 + kc0]);
    gld16(&As[c1 * 8], &A[(size_t)(m0 + r1) * K + k0 + kc1]);
    gld16(&Bs[c0 * 8], &Bw[(size_t)(n0 + r0) * K + k0 + kc0]);
    gld16(&Bs[c1 * 8], &Bw[(size_t)(n0 + r1) * K + k0 + kc1]);
    __syncthreads();

    bf16x8 af[4], bfr[4];
#pragma unroll
    for (int m = 0; m < 4; ++m)
      af[m] = *(const bf16x8*)&As[(wm + m * 16 + l15) * 32 + l4 * 8];
#pragma unroll
    for (int n = 0; n < 4; ++n)
      bfr[n] = *(const bf16x8*)&Bs[(wn + n * 16 + l15) * 32 + l4 * 8];
#pragma unroll
    for (int m = 0; m < 4; ++m)
#pragma unroll
      for (int n = 0; n < 4; ++n)
        acc[m][n] = __builtin_amdgcn_mfma_f32_16x16x32_bf16(af[m], bfr[n], acc[m][n], 0, 0, 0);
  }

  const int crow = l4 * 4;
#pragma unroll
  for (int m = 0; m < 4; ++m) {
#pragma unroll
    for (int n = 0; n < 4; ++n) {
      const int col = n0 + wn + n * 16 + l15;
      const float bv_ = bias[col];
#pragma unroll
      for (int j = 0; j < 4; ++j) {
        const int row = m0 + wm + m * 16 + crow + j;
        float v = acc[m][n][j] + bv_;
        if constexpr (SCALEQ) v *= 0.125f;      // fold 1/sqrt(dk) into Q (exact in bf16)
        if constexpr (F32OUT) Cf[(size_t)row * N + col] = v;
        else                  Cb[(size_t)row * N + col] = f2bf(v);
      }
    }
  }
}

// ---------------- V transpose: [b,s,h*64+d] -> [(b*16+h)*64+d, s] ----------------
__global__ __launch_bounds__(256)
void transpose_v(const unsigned short* __restrict__ Vp, unsigned short* __restrict__ Vt) {
  constexpr int S = 2048, Dm = 1024;
  __shared__ __align__(16) unsigned short t[64][72];
  const int bh = blockIdx.x, b = bh >> 4, h = bh & 15;
  const int s0 = blockIdx.y * 64;
  const int tid = threadIdx.x;
#pragma unroll
  for (int r = 0; r < 2; ++r) {
    const int c = r * 256 + tid;
    const int sl = c >> 3, d8 = (c & 7) * 8;
    *(bf16x8*)&t[sl][d8] =
        *(const bf16x8*)&Vp[(size_t)(b * S + s0 + sl) * Dm + h * 64 + d8];
  }
  __syncthreads();
#pragma unroll
  for (int r = 0; r < 2; ++r) {
    const int c = r * 256 + tid;
    const int dl = c >> 3, s8 = (c & 7) * 8;
    bf16x8 ov;
#pragma unroll
    for (int jj = 0; jj < 8; ++jj) ov[jj] = t[s8 + jj][dl];
    *(bf16x8*)&Vt[(size_t)(bh * 64 + dl) * S + s0 + s8] = ov;
  }
}

// ---------------- flash attention, causal, 32x32 swapped-QK^T ----------------
// Wave owns 32 q-rows. S^T = mfma(K, Q): col=q=lane&31 -> softmax fully lane-local
// (+1 cross-half shfl). O^T = mfma(V^T, P^T): col=q -> stats stay lane-local.
// Defer-max (THR=8). No LDS. Q pre-scaled by 1/8.
__global__ __launch_bounds__(256)
void attn_fwd32(const unsigned short* __restrict__ Qp,   // [B*S,1024] bf16 (scaled)
                const unsigned short* __restrict__ Kp,   // [B*S,1024] bf16
                const unsigned short* __restrict__ Vt,   // [(b*16+h)*64+d, S] bf16
                unsigned short* __restrict__ Xo) {       // [B*S,1024] bf16
  constexpr int S = 2048, Dm = 1024;
  const int bh = blockIdx.x, b = bh >> 4, h = bh & 15;
  const int w = threadIdx.x >> 6;
  const int lane = threadIdx.x & 63;
  const int l31 = lane & 31, hi = lane >> 5;
  const int y = blockIdx.y;
  // balanced causal work: every block's 4 q-blocks sum to the same step count
  const int qb = (w == 0) ? y : (w == 1) ? (31 - y) : (w == 2) ? (32 + y) : (63 - y);
  const int q0w = qb * 32;
  const int qrow = q0w + l31;

  // Q B-frags: col=q=l31, k(d)=c*16+hi*8
  const unsigned short* qptr = Qp + (size_t)(b * S + qrow) * Dm + h * 64 + hi * 8;
  bf16x8 qf[4];
#pragma unroll
  for (int c = 0; c < 4; ++c) qf[c] = *(const bf16x8*)(qptr + c * 16);

  const unsigned short* kbase = Kp + (size_t)(b * S) * Dm + h * 64 + hi * 8;
  const unsigned short* vrow0 = Vt + (size_t)(bh * 64 + l31) * S + hi * 8;
  const unsigned short* vrow1 = vrow0 + (size_t)32 * S;

  f32x16 ot0 = {}, ot1 = {};   // O^T tiles: rows d (pat), col q=l31
  float m = -1e30f, l = 0.f;

  auto step = [&](int kv0, bool masked) {
    // ---- QK^T (swapped): S^T[kv,q], two 32-kv tiles
    const unsigned short* krow0 = kbase + (size_t)(kv0 + l31) * Dm;
    const unsigned short* krow1 = krow0 + (size_t)32 * Dm;
    f32x16 t0 = {}, t1 = {};
#pragma unroll
    for (int c = 0; c < 4; ++c) {
      t0 = mfma32(*(const bf16x8*)(krow0 + c * 16), qf[c], t0);
      t1 = mfma32(*(const bf16x8*)(krow1 + c * 16), qf[c], t1);
    }
    if (masked) {
#pragma unroll
      for (int r = 0; r < 16; ++r) {
        const int kvp = kv0 + (r & 3) + 8 * (r >> 2) + 4 * hi;
        if (kvp > qrow) t0[r] = -1e9f;
        if (kvp + 32 > qrow) t1[r] = -1e9f;
      }
    }
    // ---- row max (lane-local + 1 cross-half shfl)
    float pmax = fmaxf(t0[0], t1[0]);
#pragma unroll
    for (int r = 1; r < 16; ++r) pmax = fmaxf(pmax, fmaxf(t0[r], t1[r]));
    pmax = fmaxf(pmax, __shfl_xor(pmax, 32));
    // ---- deferred rescale (T13, THR=8)
    if (__any(pmax > m + 8.f)) {
      const float mn = (pmax > m + 8.f) ? pmax : m;
      const float fct = __expf(m - mn);   // ==1 where not needed
      m = mn; l *= fct;
#pragma unroll
      for (int r = 0; r < 16; ++r) { ot0[r] *= fct; ot1[r] *= fct; }
    }
    // ---- p = exp(s - m), row-sum
    float p0[16], p1[16], ls = 0.f;
#pragma unroll
    for (int r = 0; r < 16; ++r) {
      p0[r] = __expf(t0[r] - m);
      p1[r] = __expf(t1[r] - m);
      ls += p0[r] + p1[r];
    }
    ls += __shfl_xor(ls, 32);
    l += ls;
    // ---- pack to bf16 pairs (T12) + cross-half exchange -> P^T B-frags
    unsigned ua[8], ub[8];
#pragma unroll
    for (int i = 0; i < 8; ++i) {
      ua[i] = cvtpk_bf16(p0[2 * i], p0[2 * i + 1]);
      ub[i] = cvtpk_bf16(p1[2 * i], p1[2 * i + 1]);
    }
    union FR { bf16x8 v; unsigned u[4]; } fr[4];
    {
      unsigned sa = hi ? ua[0] : ua[2], sb = hi ? ua[1] : ua[3];
      unsigned xa = __shfl_xor(sa, 32), xb = __shfl_xor(sb, 32);
      fr[0].u[0] = hi ? xa : ua[0]; fr[0].u[1] = hi ? xb : ua[1];
      fr[0].u[2] = hi ? ua[2] : xa; fr[0].u[3] = hi ? ua[3] : xb;
      unsigned sc = hi ? ua[4] : ua[6], sd = hi ? ua[5] : ua[7];
      unsigned xc = __shfl_xor(sc, 32), xd = __shfl_xor(sd, 32);
      fr[1].u[0] = hi ? xc : ua[4]; fr[1].u[1] = hi ? xd : ua[5];
      fr[1].u[2] = hi ? ua[6] : xc; fr[1].u[3] = hi ? ua[7] : xd;
      unsigned se = hi ? ub[0] : ub[2], sf = hi ? ub[1] : ub[3];
      unsigned xe = __shfl_xor(se, 32), xf = __shfl_xor(sf, 32);
      fr[2].u[0] = hi ? xe : ub[0]; fr[2].u[1] = hi ? xf : ub[1];
      fr[2].u[2] = hi ? ub[2] : xe; fr[2].u[3] = hi ? ub[3] : xf;
      unsigned sg = hi ? ub[4] : ub[6], sh = hi ? ub[5] : ub[7];
      unsigned xg = __shfl_xor(sg, 32), xh = __shfl_xor(sh, 32);
      fr[3].u[0] = hi ? xg : ub[4]; fr[3].u[1] = hi ? xh : ub[5];
      fr[3].u[2] = hi ? ub[6] : xg; fr[3].u[3] = hi ? ub[7] : xh;
    }
    // ---- O^T += V^T · P^T  (A=V^T rows d, B=P^T col q)
#pragma unroll
    for (int c = 0; c < 4; ++c) {
      const bf16x8 v0 = *(const bf16x8*)(vrow0 + kv0 + c * 16);
      const bf16x8 v1 = *(const bf16x8*)(vrow1 + kv0 + c * 16);
      ot0 = mfma32(v0, fr[c].v, ot0);
      ot1 = mfma32(v1, fr[c].v, ot1);
    }
  };

  const int kv0f = q0w & ~63;                      // exactly one masked step
  for (int kv0 = 0; kv0 < kv0f; kv0 += 64) step(kv0, false);
  step(kv0f, true);

  // ---- epilogue: normalize (lane-local l), pack pairs, 8B stores (row = qrow)
  const float inv = 1.f / l;
  unsigned short* orow = Xo + (size_t)(b * S + qrow) * Dm + h * 64;
#pragma unroll
  for (int rq = 0; rq < 4; ++rq) {
    uint2 pr;
    pr.x = cvtpk_bf16(ot0[4 * rq + 0] * inv, ot0[4 * rq + 1] * inv);
    pr.y = cvtpk_bf16(ot0[4 * rq + 2] * inv, ot0[4 * rq + 3] * inv);
    *(uint2*)(orow + 8 * rq + 4 * hi) = pr;
    uint2 pr1;
    pr1.x = cvtpk_bf16(ot1[4 * rq + 0] * inv, ot1[4 * rq + 1] * inv);
    pr1.y = cvtpk_bf16(ot1[4 * rq + 2] * inv, ot1[4 * rq + 3] * inv);
    *(uint2*)(orow + 32 + 8 * rq + 4 * hi) = pr1;
  }
}

// ---------------- launch ----------------
extern "C" void kernel_launch(void* const* d_in, const int* in_sizes, int n_in,
                              void* d_out, int out_size, void* d_ws, size_t ws_size,
                              hipStream_t stream) {
  const float* query = (const float*)d_in[0];
  const float* key   = (const float*)d_in[1];
  const float* value = (const float*)d_in[2];
  const float* Wq = (const float*)d_in[4];
  const float* bq = (const float*)d_in[5];
  const float* Wk = (const float*)d_in[6];
  const float* bk = (const float*)d_in[7];
  const float* Wv = (const float*)d_in[8];
  const float* bv = (const float*)d_in[9];
  const float* Wo = (const float*)d_in[10];
  const float* bo = (const float*)d_in[11];

  constexpr int B = 4, S = 2048, D = 1024;
  constexpr int M = B * S;
  const size_t MB = 1024u * 1024u;
  uint8_t* ws = (uint8_t*)d_ws;

  unsigned short* Xq  = (unsigned short*)(ws + 0);
  unsigned short* Xk  = (unsigned short*)(ws + 16 * MB);
  unsigned short* Xv  = (unsigned short*)(ws + 32 * MB);
  unsigned short* Wqb = (unsigned short*)(ws + 48 * MB);
  unsigned short* Wkb = (unsigned short*)(ws + 50 * MB);
  unsigned short* Wvb = (unsigned short*)(ws + 52 * MB);
  unsigned short* Wob = (unsigned short*)(ws + 54 * MB);
  unsigned short* Qp  = (unsigned short*)(ws + 56 * MB);
  unsigned short* Kp  = (unsigned short*)(ws + 72 * MB);
  unsigned short* Vp  = (unsigned short*)(ws + 0);        // reuse Xq
  unsigned short* Vt  = (unsigned short*)(ws + 32 * MB);  // reuse Xv
  unsigned short* Xat = (unsigned short*)(ws + 16 * MB);  // reuse Xk

  const int nAct4 = M * D / 4, nW4 = D * D / 4;
  cast_bf16<<<(nAct4 + 255) / 256, 256, 0, stream>>>(query, Xq, nAct4);
  cast_bf16<<<(nAct4 + 255) / 256, 256, 0, stream>>>(key,   Xk, nAct4);
  cast_bf16<<<(nAct4 + 255) / 256, 256, 0, stream>>>(value, Xv, nAct4);
  cast_bf16<<<(nW4 + 255) / 256, 256, 0, stream>>>(Wq, Wqb, nW4);
  cast_bf16<<<(nW4 + 255) / 256, 256, 0, stream>>>(Wk, Wkb, nW4);
  cast_bf16<<<(nW4 + 255) / 256, 256, 0, stream>>>(Wv, Wvb, nW4);
  cast_bf16<<<(nW4 + 255) / 256, 256, 0, stream>>>(Wo, Wob, nW4);

  dim3 gg(D / 128, M / 128);
  gemm_bt<false, true ><<<gg, 256, 0, stream>>>(Xq, Wqb, bq, Qp, nullptr, M, D, D);
  gemm_bt<false, false><<<gg, 256, 0, stream>>>(Xk, Wkb, bk, Kp, nullptr, M, D, D);
  gemm_bt<false, false><<<gg, 256, 0, stream>>>(Xv, Wvb, bv, Vp, nullptr, M, D, D);

  transpose_v<<<dim3(64, S / 64), 256, 0, stream>>>(Vp, Vt);

  attn_fwd32<<<dim3(64, 16), 256, 0, stream>>>(Qp, Kp, Vt, Xat);

  gemm_bt<true, false><<<gg, 256, 0, stream>>>(Xat, Wob, bo, nullptr, (float*)d_out, M, D, D);
}

// Round 3
// 300.388 us; speedup vs baseline: 1.4513x; 1.0686x over previous
//
#include <hip/hip_runtime.h>
#include <cstdint>
#include <cstddef>

// MHA: out = softmax_causal((XqWq^T+bq)(XkWk^T+bk)^T / 8) (XvWv^T+bv) Wo^T + bo
// B=4 S=2048 D=1024 H=16 dk=64. bf16 MFMA, fp32 accum. Softmax in exp2 domain:
// Q projection pre-scaled by 0.125*log2(e).
// ws: [0,16M) Xq->Vp ; [16M,32M) Xk->Xattn ; [32M,48M) Xv->Vt ;
// [48M,56M) weights bf16 ; [56M,72M) Qp ; [72M,88M) Kp.

typedef __attribute__((ext_vector_type(8))) short bf16x8;
typedef __attribute__((ext_vector_type(4))) float f32x4;
typedef __attribute__((ext_vector_type(16))) float f32x16;

__device__ __forceinline__ unsigned short f2bf(float f) {
  union { float f; unsigned u; } x; x.f = f;
  unsigned r = x.u + 0x7FFFu + ((x.u >> 16) & 1u);   // RNE
  return (unsigned short)(r >> 16);
}

__device__ __forceinline__ unsigned cvtpk_bf16(float lo, float hi) {
  unsigned r;
  asm("v_cvt_pk_bf16_f32 %0, %1, %2" : "=v"(r) : "v"(lo), "v"(hi));
  return r;
}

__device__ __forceinline__ f32x16 mfma32(bf16x8 a, bf16x8 b, f32x16 c) {
  return __builtin_amdgcn_mfma_f32_32x32x16_bf16(a, b, c, 0, 0, 0);
}

__device__ __forceinline__ void gld16(unsigned short* lds, const unsigned short* g) {
  __builtin_amdgcn_global_load_lds(
      (const __attribute__((address_space(1))) unsigned int*)g,
      (__attribute__((address_space(3))) unsigned int*)lds, 16, 0, 0);
}

// ---------------- fp32 -> bf16 cast ----------------
__global__ __launch_bounds__(256) void cast_bf16(const float* __restrict__ src,
                                                 unsigned short* __restrict__ dst, int n4) {
  const int i = blockIdx.x * 256 + threadIdx.x;
  if (i >= n4) return;
  const float4 f = ((const float4*)src)[i];
  ushort4 o;
  o.x = f2bf(f.x); o.y = f2bf(f.y); o.z = f2bf(f.z); o.w = f2bf(f.w);
  ((ushort4*)dst)[i] = o;
}

// ---------------- GEMM: C[m,n] = sum_k A[m,k]*W[n,k] + bias[n] ----------------
template <bool F32OUT, bool SCALEQ>
__global__ __launch_bounds__(256)
void gemm_bt(const unsigned short* __restrict__ A,
             const unsigned short* __restrict__ Bw,
             const float* __restrict__ bias,
             unsigned short* __restrict__ Cb,
             float* __restrict__ Cf,
             int M, int N, int K) {
  __shared__ unsigned short As[128 * 32];
  __shared__ unsigned short Bs[128 * 32];
  const int tid = threadIdx.x;
  const int lane = tid & 63;
  const int w = tid >> 6;
  const int wm = (w >> 1) * 64;
  const int wn = (w & 1) * 64;
  const int m0 = blockIdx.y * 128;
  const int n0 = blockIdx.x * 128;
  const int l15 = lane & 15, l4 = lane >> 4;

  f32x4 acc[4][4] = {};

  const int c0 = tid, c1 = 256 + tid;
  const int r0 = c0 >> 2, kc0 = (c0 & 3) * 8;
  const int r1 = c1 >> 2, kc1 = (c1 & 3) * 8;

  for (int k0 = 0; k0 < K; k0 += 32) {
    __syncthreads();
    gld16(&As[c0 * 8], &A[(size_t)(m0 + r0) * K + k0 + kc0]);
    gld16(&As[c1 * 8], &A[(size_t)(m0 + r1) * K + k0 + kc1]);
    gld16(&Bs[c0 * 8], &Bw[(size_t)(n0 + r0) * K + k0 + kc0]);
    gld16(&Bs[c1 * 8], &Bw[(size_t)(n0 + r1) * K + k0 + kc1]);
    __syncthreads();

    bf16x8 af[4], bfr[4];
#pragma unroll
    for (int m = 0; m < 4; ++m)
      af[m] = *(const bf16x8*)&As[(wm + m * 16 + l15) * 32 + l4 * 8];
#pragma unroll
    for (int n = 0; n < 4; ++n)
      bfr[n] = *(const bf16x8*)&Bs[(wn + n * 16 + l15) * 32 + l4 * 8];
#pragma unroll
    for (int m = 0; m < 4; ++m)
#pragma unroll
      for (int n = 0; n < 4; ++n)
        acc[m][n] = __builtin_amdgcn_mfma_f32_16x16x32_bf16(af[m], bfr[n], acc[m][n], 0, 0, 0);
  }

  const int crow = l4 * 4;
#pragma unroll
  for (int m = 0; m < 4; ++m) {
#pragma unroll
    for (int n = 0; n < 4; ++n) {
      const int col = n0 + wn + n * 16 + l15;
      const float bv_ = bias[col];
#pragma unroll
      for (int j = 0; j < 4; ++j) {
        const int row = m0 + wm + m * 16 + crow + j;
        float v = acc[m][n][j] + bv_;
        if constexpr (SCALEQ) v *= 0.125f * 1.44269504f;  // 1/sqrt(dk) * log2(e)
        if constexpr (F32OUT) Cf[(size_t)row * N + col] = v;
        else                  Cb[(size_t)row * N + col] = f2bf(v);
      }
    }
  }
}

// ---------------- V transpose: [b,s,h*64+d] -> [(b*16+h)*64+d, s] ----------------
__global__ __launch_bounds__(256)
void transpose_v(const unsigned short* __restrict__ Vp, unsigned short* __restrict__ Vt) {
  constexpr int S = 2048, Dm = 1024;
  __shared__ __align__(16) unsigned short t[64][72];
  const int bh = blockIdx.x, b = bh >> 4, h = bh & 15;
  const int s0 = blockIdx.y * 64;
  const int tid = threadIdx.x;
#pragma unroll
  for (int r = 0; r < 2; ++r) {
    const int c = r * 256 + tid;
    const int sl = c >> 3, d8 = (c & 7) * 8;
    *(bf16x8*)&t[sl][d8] =
        *(const bf16x8*)&Vp[(size_t)(b * S + s0 + sl) * Dm + h * 64 + d8];
  }
  __syncthreads();
#pragma unroll
  for (int r = 0; r < 2; ++r) {
    const int c = r * 256 + tid;
    const int dl = c >> 3, s8 = (c & 7) * 8;
    bf16x8 ov;
#pragma unroll
    for (int jj = 0; jj < 8; ++jj) ov[jj] = t[s8 + jj][dl];
    *(bf16x8*)&Vt[(size_t)(bh * 64 + dl) * S + s0 + s8] = ov;
  }
}

// ---------------- flash attention, causal, 1 wave per 32-row q-block ----------------
// Swapped QK^T (col=q lane-local softmax), O^T via A=V^T. KVBLK=32.
// K register-prefetch (ping-pong kA/kB), V issued at body start. exp2 domain.
// Grid: (64 bh, 64 qblk) 1-wave blocks, longest-first for scheduler packing.
__global__ __launch_bounds__(64)
void attn_fwd32p(const unsigned short* __restrict__ Qp,   // [B*S,1024] bf16 (scaled)
                 const unsigned short* __restrict__ Kp,   // [B*S,1024] bf16
                 const unsigned short* __restrict__ Vt,   // [(b*16+h)*64+d, S] bf16
                 unsigned short* __restrict__ Xo) {       // [B*S,1024] bf16
  constexpr int S = 2048, Dm = 1024;
  const int bh = blockIdx.x, b = bh >> 4, h = bh & 15;
  const int lane = threadIdx.x & 63;
  const int l31 = lane & 31, hi = lane >> 5;
  const int qb = 63 - (int)blockIdx.y;   // longest ranges dispatched first
  const int qrow = qb * 32 + l31;
  const int nt = qb + 1;                 // KV tiles of 32; last one masked

  // Q B-frags: col=q=l31, k(d)=c*16+hi*8
  const unsigned short* qptr = Qp + (size_t)(b * S + qrow) * Dm + h * 64 + hi * 8;
  bf16x8 qf[4];
#pragma unroll
  for (int c = 0; c < 4; ++c) qf[c] = *(const bf16x8*)(qptr + c * 16);

  const unsigned short* kbase = Kp + (size_t)(b * S) * Dm + h * 64 + hi * 8;
  const unsigned short* vr0 = Vt + (size_t)(bh * 64 + l31) * S + hi * 8;
  const unsigned short* vr1 = vr0 + (size_t)32 * S;

  f32x16 ot0 = {}, ot1 = {};   // O^T: rows d (0-31 / 32-63), col q=l31
  float m = -1e30f, l = 0.f;

  auto loadK = [&](bf16x8 (&kr)[4], int t) {
    const unsigned short* krow = kbase + (size_t)(t * 32 + l31) * Dm;
#pragma unroll
    for (int c = 0; c < 4; ++c) kr[c] = *(const bf16x8*)(krow + c * 16);
  };

  auto body = [&](bf16x8 (&kr)[4], int t) {
    const int kv0 = t * 32;
    // V loads issued early; consumed after softmax (~600cy later)
    const bf16x8 vf0a = *(const bf16x8*)(vr0 + kv0);
    const bf16x8 vf0b = *(const bf16x8*)(vr0 + kv0 + 16);
    const bf16x8 vf1a = *(const bf16x8*)(vr1 + kv0);
    const bf16x8 vf1b = *(const bf16x8*)(vr1 + kv0 + 16);
    // S^T = K · Q  (rows kv, col q)
    f32x16 ts = {};
#pragma unroll
    for (int c = 0; c < 4; ++c) ts = mfma32(kr[c], qf[c], ts);
    if (t == nt - 1) {   // diagonal tile
#pragma unroll
      for (int r = 0; r < 16; ++r) {
        const int kvp = kv0 + (r & 3) + 8 * (r >> 2) + 4 * hi;
        if (kvp > qrow) ts[r] = -1e9f;
      }
    }
    // row max: lane-local + 1 cross-half shfl
    float pmax = ts[0];
#pragma unroll
    for (int r = 1; r < 16; ++r) pmax = fmaxf(pmax, ts[r]);
    pmax = fmaxf(pmax, __shfl_xor(pmax, 32));
    // deferred rescale (T13; log2 units)
    if (__any(pmax > m + 11.5f)) {
      const float mn = (pmax > m + 11.5f) ? pmax : m;
      const float fct = __builtin_amdgcn_exp2f(m - mn);
      m = mn; l *= fct;
#pragma unroll
      for (int r = 0; r < 16; ++r) { ot0[r] *= fct; ot1[r] *= fct; }
    }
    // p = 2^(s-m), row-sum
    float p[16], ls = 0.f;
#pragma unroll
    for (int r = 0; r < 16; ++r) {
      p[r] = __builtin_amdgcn_exp2f(ts[r] - m);
      ls += p[r];
    }
    ls += __shfl_xor(ls, 32);
    l += ls;
    // pack bf16 pairs + cross-half exchange -> P^T B-frags (k=kv)
    unsigned ua[8];
#pragma unroll
    for (int i = 0; i < 8; ++i) ua[i] = cvtpk_bf16(p[2 * i], p[2 * i + 1]);
    union FR { bf16x8 v; unsigned u[4]; } fr0, fr1;
    {
      unsigned sa = hi ? ua[0] : ua[2], sb = hi ? ua[1] : ua[3];
      unsigned xa = __shfl_xor(sa, 32), xb = __shfl_xor(sb, 32);
      fr0.u[0] = hi ? xa : ua[0]; fr0.u[1] = hi ? xb : ua[1];
      fr0.u[2] = hi ? ua[2] : xa; fr0.u[3] = hi ? ua[3] : xb;
      unsigned sc = hi ? ua[4] : ua[6], sd = hi ? ua[5] : ua[7];
      unsigned xc = __shfl_xor(sc, 32), xd = __shfl_xor(sd, 32);
      fr1.u[0] = hi ? xc : ua[4]; fr1.u[1] = hi ? xd : ua[5];
      fr1.u[2] = hi ? ua[6] : xc; fr1.u[3] = hi ? ua[7] : xd;
    }
    // O^T += V^T · P^T
    ot0 = mfma32(vf0a, fr0.v, ot0);
    ot0 = mfma32(vf0b, fr1.v, ot0);
    ot1 = mfma32(vf1a, fr0.v, ot1);
    ot1 = mfma32(vf1b, fr1.v, ot1);
  };

  // ping-pong K prefetch (named sets, static indexing)
  bf16x8 kA[4], kB[4];
  loadK(kA, 0);
  int t = 0;
  for (; t + 2 <= nt; t += 2) {
    loadK(kB, t + 1);
    body(kA, t);
    if (t + 2 < nt) loadK(kA, t + 2);
    body(kB, t + 1);
  }
  if (t < nt) body(kA, t);

  // epilogue: normalize (lane-local l), pack pairs, 8B stores
  const float inv = 1.f / l;
  unsigned short* orow = Xo + (size_t)(b * S + qrow) * Dm + h * 64;
#pragma unroll
  for (int rq = 0; rq < 4; ++rq) {
    uint2 pr;
    pr.x = cvtpk_bf16(ot0[4 * rq + 0] * inv, ot0[4 * rq + 1] * inv);
    pr.y = cvtpk_bf16(ot0[4 * rq + 2] * inv, ot0[4 * rq + 3] * inv);
    *(uint2*)(orow + 8 * rq + 4 * hi) = pr;
    uint2 pr1;
    pr1.x = cvtpk_bf16(ot1[4 * rq + 0] * inv, ot1[4 * rq + 1] * inv);
    pr1.y = cvtpk_bf16(ot1[4 * rq + 2] * inv, ot1[4 * rq + 3] * inv);
    *(uint2*)(orow + 32 + 8 * rq + 4 * hi) = pr1;
  }
}

// ---------------- launch ----------------
extern "C" void kernel_launch(void* const* d_in, const int* in_sizes, int n_in,
                              void* d_out, int out_size, void* d_ws, size_t ws_size,
                              hipStream_t stream) {
  const float* query = (const float*)d_in[0];
  const float* key   = (const float*)d_in[1];
  const float* value = (const float*)d_in[2];
  const float* Wq = (const float*)d_in[4];
  const float* bq = (const float*)d_in[5];
  const float* Wk = (const float*)d_in[6];
  const float* bk = (const float*)d_in[7];
  const float* Wv = (const float*)d_in[8];
  const float* bv = (const float*)d_in[9];
  const float* Wo = (const float*)d_in[10];
  const float* bo = (const float*)d_in[11];

  constexpr int B = 4, S = 2048, D = 1024;
  constexpr int M = B * S;
  const size_t MB = 1024u * 1024u;
  uint8_t* ws = (uint8_t*)d_ws;

  unsigned short* Xq  = (unsigned short*)(ws + 0);
  unsigned short* Xk  = (unsigned short*)(ws + 16 * MB);
  unsigned short* Xv  = (unsigned short*)(ws + 32 * MB);
  unsigned short* Wqb = (unsigned short*)(ws + 48 * MB);
  unsigned short* Wkb = (unsigned short*)(ws + 50 * MB);
  unsigned short* Wvb = (unsigned short*)(ws + 52 * MB);
  unsigned short* Wob = (unsigned short*)(ws + 54 * MB);
  unsigned short* Qp  = (unsigned short*)(ws + 56 * MB);
  unsigned short* Kp  = (unsigned short*)(ws + 72 * MB);
  unsigned short* Vp  = (unsigned short*)(ws + 0);        // reuse Xq
  unsigned short* Vt  = (unsigned short*)(ws + 32 * MB);  // reuse Xv
  unsigned short* Xat = (unsigned short*)(ws + 16 * MB);  // reuse Xk

  const int nAct4 = M * D / 4, nW4 = D * D / 4;
  cast_bf16<<<(nAct4 + 255) / 256, 256, 0, stream>>>(query, Xq, nAct4);
  cast_bf16<<<(nAct4 + 255) / 256, 256, 0, stream>>>(key,   Xk, nAct4);
  cast_bf16<<<(nAct4 + 255) / 256, 256, 0, stream>>>(value, Xv, nAct4);
  cast_bf16<<<(nW4 + 255) / 256, 256, 0, stream>>>(Wq, Wqb, nW4);
  cast_bf16<<<(nW4 + 255) / 256, 256, 0, stream>>>(Wk, Wkb, nW4);
  cast_bf16<<<(nW4 + 255) / 256, 256, 0, stream>>>(Wv, Wvb, nW4);
  cast_bf16<<<(nW4 + 255) / 256, 256, 0, stream>>>(Wo, Wob, nW4);

  dim3 gg(D / 128, M / 128);
  gemm_bt<false, true ><<<gg, 256, 0, stream>>>(Xq, Wqb, bq, Qp, nullptr, M, D, D);
  gemm_bt<false, false><<<gg, 256, 0, stream>>>(Xk, Wkb, bk, Kp, nullptr, M, D, D);
  gemm_bt<false, false><<<gg, 256, 0, stream>>>(Xv, Wvb, bv, Vp, nullptr, M, D, D);

  transpose_v<<<dim3(64, S / 64), 256, 0, stream>>>(Vp, Vt);

  attn_fwd32p<<<dim3(64, 64), 64, 0, stream>>>(Qp, Kp, Vt, Xat);

  gemm_bt<true, false><<<gg, 256, 0, stream>>>(Xat, Wob, bo, nullptr, (float*)d_out, M, D, D);
}